// Round 5
// baseline (147.177 us; speedup 1.0000x reference)
//
#include <hip/hip_runtime.h>
#include <hip/hip_bf16.h>
#include <math.h>

#define SEQ 16384
#define D   1024
#define NBLK_DOT 8192   // 4 waves/block, 1 row/wave -> 4 rows/block
                        // 32768 waves = 4 resident generations

typedef float floatx4 __attribute__((ext_vector_type(4)));

// ---------------------------------------------------------------------------
// Kernel 1: logits + per-block softmax partials.
// One row per wave; 4 independent dwordx4 loads issued together; 6-stage
// butterfly reduce; lane 0 stores. 4 generations of block turnover keep the
// memory system continuously fed as waves retire.
// Blocks 0..4095 -> head 0, 4096..8191 -> head 1.
// ---------------------------------------------------------------------------
__global__ __launch_bounds__(256) void dot_partial_kernel(
    const float* __restrict__ g1, const float* __restrict__ g2,
    const float* __restrict__ wp1, const float* __restrict__ wp2,
    float* __restrict__ logits,
    float* __restrict__ blk_m, float* __restrict__ blk_s) {
  const int lane = threadIdx.x & 63;
  const int wid  = threadIdx.x >> 6;                 // 0..3
  const int r    = blockIdx.x * 4 + wid;             // global row 0..32767
  const bool head1 = (blockIdx.x >= NBLK_DOT / 2);
  const float* g  = head1 ? g2 : g1;
  const float* wp = head1 ? wp2 : wp1;
  const int row   = head1 ? (r - SEQ) : r;

  floatx4 wv0 = *((const floatx4*)wp + lane);
  floatx4 wv1 = *((const floatx4*)wp + lane + 64);
  floatx4 wv2 = *((const floatx4*)wp + lane + 128);
  floatx4 wv3 = *((const floatx4*)wp + lane + 192);

  const floatx4* rv = (const floatx4*)(g + (size_t)row * D);
  floatx4 a0 = rv[lane];
  floatx4 a1 = rv[lane + 64];
  floatx4 a2 = rv[lane + 128];
  floatx4 a3 = rv[lane + 192];

  float acc = 0.f;
#pragma unroll
  for (int e = 0; e < 4; ++e) {
    acc = fmaf(a0[e], wv0[e], acc);
    acc = fmaf(a1[e], wv1[e], acc);
    acc = fmaf(a2[e], wv2[e], acc);
    acc = fmaf(a3[e], wv3[e], acc);
  }
#pragma unroll
  for (int off = 32; off > 0; off >>= 1)
    acc += __shfl_xor(acc, off, 64);

  if (lane == 0) logits[r] = acc;

  // block softmax partial over 4 rows (one per wave)
  __shared__ float lv[4];
  if (lane == 0) lv[wid] = acc;
  __syncthreads();
  if (threadIdx.x == 0) {
    float M = fmaxf(fmaxf(lv[0], lv[1]), fmaxf(lv[2], lv[3]));
    float S = __expf(lv[0] - M) + __expf(lv[1] - M) +
              __expf(lv[2] - M) + __expf(lv[3] - M);
    blk_m[blockIdx.x] = M;
    blk_s[blockIdx.x] = S;
  }
}

// ---------------------------------------------------------------------------
// Kernel 2: fused stats + normalize. 32 blocks x 256 threads.
// Blocks 0..15 -> head 0, 16..31 -> head 1. Each block redundantly reduces
// its head's 4096 (m,s) partials (32 KB, L2-hot), then normalizes its
// 256-float4 slice of the output.
// ---------------------------------------------------------------------------
__global__ __launch_bounds__(256) void finalize_kernel(
    const float* __restrict__ blk_m, const float* __restrict__ blk_s,
    const float4* __restrict__ logits4, float4* __restrict__ out4) {
  const int head = blockIdx.x >> 4;          // 16 blocks per head
  const int tid  = threadIdx.x;
  const int lane = tid & 63;
  const int wid  = tid >> 6;

  // --- reduce 4096 partials: 16 per thread ---
  const float* pm = blk_m + head * (NBLK_DOT / 2) + tid * 16;
  const float* ps = blk_s + head * (NBLK_DOT / 2) + tid * 16;
  float M = -INFINITY, S = 0.f;
#pragma unroll
  for (int i = 0; i < 16; ++i) {
    float m = pm[i], s = ps[i];
    float nm = fmaxf(M, m);
    S = S * __expf(M - nm) + s * __expf(m - nm);
    M = nm;
  }
#pragma unroll
  for (int off = 32; off > 0; off >>= 1) {
    float m2 = __shfl_xor(M, off, 64);
    float s2 = __shfl_xor(S, off, 64);
    float nm = fmaxf(M, m2);
    S = S * __expf(M - nm) + s2 * __expf(m2 - nm);
    M = nm;
  }
  __shared__ float sm[4], ss[4], fin[2];
  if (lane == 0) { sm[wid] = M; ss[wid] = S; }
  __syncthreads();
  if (tid == 0) {
    float Mg = -INFINITY, Sg = 0.f;
#pragma unroll
    for (int i = 0; i < 4; ++i) {
      float nm = fmaxf(Mg, sm[i]);
      Sg = Sg * __expf(Mg - nm) + ss[i] * __expf(sm[i] - nm);
      Mg = nm;
    }
    fin[0] = Mg;
    fin[1] = 1.0f / Sg;
  }
  __syncthreads();
  const float Mg   = fin[0];
  const float invS = fin[1];

  // --- normalize this block's slice: 256 float4 ---
  const int i = head * 4096 + (blockIdx.x & 15) * 256 + tid;
  float4 v = logits4[i];
  float4 o;
  o.x = __expf(v.x - Mg) * invS;
  o.y = __expf(v.y - Mg) * invS;
  o.z = __expf(v.z - Mg) * invS;
  o.w = __expf(v.w - Mg) * invS;
  out4[i] = o;
}

extern "C" void kernel_launch(void* const* d_in, const int* in_sizes, int n_in,
                              void* d_out, int out_size, void* d_ws, size_t ws_size,
                              hipStream_t stream) {
  const float* g1  = (const float*)d_in[0];
  const float* g2  = (const float*)d_in[1];
  const float* wp1 = (const float*)d_in[2];
  const float* wp2 = (const float*)d_in[3];
  float* out = (float*)d_out;

  float* logits = (float*)d_ws;              // 32768 floats
  float* blk_m  = logits + 2 * SEQ;          // 8192
  float* blk_s  = blk_m + NBLK_DOT;          // 8192

  dot_partial_kernel<<<NBLK_DOT, 256, 0, stream>>>(g1, g2, wp1, wp2,
                                                   logits, blk_m, blk_s);
  finalize_kernel<<<32, 256, 0, stream>>>(blk_m, blk_s,
                                          (const float4*)logits, (float4*)out);
}